// Round 2
// baseline (695.584 us; speedup 1.0000x reference)
//
#include <hip/hip_runtime.h>

#define Bsz  2048
#define Tlen 512
#define Din  32
#define Hd   64

typedef _Float16 half8 __attribute__((ext_vector_type(8)));
typedef float    f32x4 __attribute__((ext_vector_type(4)));

// LDS h-tile row stride in f16 elems: 72 -> 144B rows, keeps ds_read_b128 16B-aligned
#define HS 72

__device__ __forceinline__ float sigm(float x) {
    return __builtin_amdgcn_rcpf(1.0f + __builtin_amdgcn_exp2f(-1.442695041f * x));
}
__device__ __forceinline__ float tanh_(float x) {
    return 2.0f * __builtin_amdgcn_rcpf(1.0f + __builtin_amdgcn_exp2f(-2.885390082f * x)) - 1.0f;
}
__device__ __forceinline__ half8 load8(const float* p) {
    half8 r;
#pragma unroll
    for (int j = 0; j < 8; ++j) r[j] = (_Float16)p[j];
    return r;
}

#define MFMA(a, b, c) __builtin_amdgcn_mfma_f32_16x16x32_f16((a), (b), (c), 0, 0, 0)

__global__ __launch_bounds__(512, 2)
void gru_fused(const float* __restrict__ x,
               const float* __restrict__ Wih0, const float* __restrict__ Whh0,
               const float* __restrict__ bih0, const float* __restrict__ bhh0,
               const float* __restrict__ Wih1, const float* __restrict__ Whh1,
               const float* __restrict__ bih1, const float* __restrict__ bhh1,
               const float* __restrict__ fcw,  const float* __restrict__ fcb,
               float* __restrict__ out)
{
    // double-buffered h tiles (f16, MFMA A-operand staging); rows 8..15 stay 0
    __shared__ _Float16 h1b[2][16][HS];
    __shared__ _Float16 h2b[2][16][HS];
    __shared__ float hfin[8][Hd];

    const int tid  = threadIdx.x;
    const int lane = tid & 63;
    const int wave = tid >> 6;
    const int grp  = wave >> 2;            // 0 = layer1 waves, 1 = layer2 waves
    const int wg   = wave & 3;             // which 16 gate-cols this wave owns
    const int m    = lane & 15;            // A-frag row (batch)
    const int quad = lane >> 4;            // k-chunk (A/B), row-group (C/D)
    const int col  = (wg << 4) + m;        // gate/h column 0..63
    const int b0   = blockIdx.x << 3;      // 8 batches per block

    // split-wave gate ownership: quads 0/1 own C-rows q*4+{0,1},
    // quads 2/3 take partner's (lane^32) C-rows q*4+{2,3}. rows 0..7 = real batches.
    const int q    = quad & 1;
    const int hi   = quad >> 1;
    const int row0 = q * 4 + hi * 2;       // first of the two rows this lane owns

    // zero-init LDS state (h[-1] = 0; ghost rows stay 0 forever)
    for (int idx = tid; idx < 2 * 16 * HS; idx += 512) {
        (&h1b[0][0][0])[idx] = (_Float16)0.f;
        (&h2b[0][0][0])[idx] = (_Float16)0.f;
    }

    // ---- persistent weight B-fragments in VGPRs (B[k][n] = W[n][k]) ----
    half8 wx[2][3], wh[2][3];
    float brz0, brz1, bin_, bhn_;

    if (grp == 0) {
#pragma unroll
        for (int gt = 0; gt < 3; ++gt) {
            const int g = gt * 64 + col;
            wx[0][gt] = load8(Wih0 + g * Din + quad * 8);
#pragma unroll
            for (int kb = 0; kb < 2; ++kb)
                wh[kb][gt] = load8(Whh0 + g * Hd + kb * 32 + quad * 8);
        }
        brz0 = bih0[col] + bhh0[col];
        brz1 = bih0[64 + col] + bhh0[64 + col];
        bin_ = bih0[128 + col];
        bhn_ = bhh0[128 + col];
    } else {
#pragma unroll
        for (int gt = 0; gt < 3; ++gt) {
            const int g = gt * 64 + col;
#pragma unroll
            for (int kb = 0; kb < 2; ++kb) {
                wx[kb][gt] = load8(Wih1 + g * Hd + kb * 32 + quad * 8);
                wh[kb][gt] = load8(Whh1 + g * Hd + kb * 32 + quad * 8);
            }
        }
        brz0 = bih1[col] + bhh1[col];
        brz1 = bih1[64 + col] + bhh1[64 + col];
        bin_ = bih1[128 + col];
        bhn_ = bhh1[128 + col];
    }

    // x prefetch registers (L1 waves). Ghost lanes (m>=8) alias batch m-8:
    // their A-rows only feed ghost C-rows, which are never consumed.
    const float* xp = x + ((size_t)(b0 + (m & 7)) * Tlen) * Din + quad * 8;
    float4 xa, xb;
    if (grp == 0) {
        xa = *(const float4*)xp;
        xb = *(const float4*)(xp + 4);
    }

    float hst[2] = {0.f, 0.f};             // state for the 2 owned rows, this col
    __syncthreads();

    // pipelined recurrence: iter i -> L1 computes h1[i], L2 computes h2[i-1]
    for (int i = 0; i <= Tlen; ++i) {
        const int rb = (i + 1) & 1;        // read buffer  = (i-1)&1
        const int wb = i & 1;              // write buffer
        const bool act = (grp == 0) ? (i < Tlen) : (i >= 1);
        if (act) {
            // bias baked into accumulator init (MFMA is linear in C)
            f32x4 ar  = {brz0, brz0, brz0, brz0};
            f32x4 az  = {brz1, brz1, brz1, brz1};
            f32x4 anx = {bin_, bin_, bin_, bin_};
            f32x4 anh = {bhn_, bhn_, bhn_, bhn_};
            half8 ah0, ah1;
            if (grp == 0) {
                // issue prefetch of x[t+1] first — latency hidden behind this step
                const float* xn = xp + ((i + 1 < Tlen) ? Din : 0);
                float4 pa = *(const float4*)xn;
                float4 pb = *(const float4*)(xn + 4);

                half8 ax;
                ax[0] = (_Float16)xa.x; ax[1] = (_Float16)xa.y;
                ax[2] = (_Float16)xa.z; ax[3] = (_Float16)xa.w;
                ax[4] = (_Float16)xb.x; ax[5] = (_Float16)xb.y;
                ax[6] = (_Float16)xb.z; ax[7] = (_Float16)xb.w;

                ah0 = *(const half8*)&h1b[rb][m][quad * 8];
                ah1 = *(const half8*)&h1b[rb][m][32 + quad * 8];
                ar  = MFMA(ax, wx[0][0], ar);
                az  = MFMA(ax, wx[0][1], az);
                anx = MFMA(ax, wx[0][2], anx);

                xa = pa; xb = pb; xp = xn;
            } else {
                half8 ax0 = *(const half8*)&h1b[rb][m][quad * 8];       // h1[i-1]
                half8 ax1 = *(const half8*)&h1b[rb][m][32 + quad * 8];
                ah0 = *(const half8*)&h2b[rb][m][quad * 8];             // h2[i-2]
                ah1 = *(const half8*)&h2b[rb][m][32 + quad * 8];
                ar  = MFMA(ax0, wx[0][0], ar);  ar  = MFMA(ax1, wx[1][0], ar);
                az  = MFMA(ax0, wx[0][1], az);  az  = MFMA(ax1, wx[1][1], az);
                anx = MFMA(ax0, wx[0][2], anx); anx = MFMA(ax1, wx[1][2], anx);
            }
            ar  = MFMA(ah0, wh[0][0], ar);  ar  = MFMA(ah1, wh[1][0], ar);
            az  = MFMA(ah0, wh[0][1], az);  az  = MFMA(ah1, wh[1][1], az);
            anh = MFMA(ah0, wh[0][2], anh); anh = MFMA(ah1, wh[1][2], anh);

            // redistribute: upper quads take partner's rows {2,3} accums
            float g_r[2], g_z[2], g_nx[2], g_nh[2], t;
            t = __shfl_xor(ar[2],  32); g_r[0]  = hi ? t : ar[0];
            t = __shfl_xor(ar[3],  32); g_r[1]  = hi ? t : ar[1];
            t = __shfl_xor(az[2],  32); g_z[0]  = hi ? t : az[0];
            t = __shfl_xor(az[3],  32); g_z[1]  = hi ? t : az[1];
            t = __shfl_xor(anx[2], 32); g_nx[0] = hi ? t : anx[0];
            t = __shfl_xor(anx[3], 32); g_nx[1] = hi ? t : anx[1];
            t = __shfl_xor(anh[2], 32); g_nh[0] = hi ? t : anh[0];
            t = __shfl_xor(anh[3], 32); g_nh[1] = hi ? t : anh[1];

            _Float16* dst = (grp == 0) ? &h1b[wb][0][0] : &h2b[wb][0][0];
#pragma unroll
            for (int r = 0; r < 2; ++r) {
                float rr = sigm(g_r[r]);
                float zz = sigm(g_z[r]);
                float nn = tanh_(g_nx[r] + rr * g_nh[r]);
                hst[r] = (1.f - zz) * nn + zz * hst[r];
                dst[(row0 + r) * HS + col] = (_Float16)hst[r];
            }
        }
        __syncthreads();   // write(i) -> read(i+1); also protects WAR across buffers
    }

    // hst of layer-2 waves holds h2[T-1] rows row0+{0,1}; FC head
    if (grp == 1) {
#pragma unroll
        for (int r = 0; r < 2; ++r) hfin[row0 + r][col] = hst[r];
    }
    __syncthreads();
    if (tid < 8) {
        float acc = fcb[0];
        for (int c = 0; c < Hd; ++c) acc += hfin[tid][c] * fcw[c];
        out[b0 + tid] = acc;
    }
}

extern "C" void kernel_launch(void* const* d_in, const int* in_sizes, int n_in,
                              void* d_out, int out_size, void* d_ws, size_t ws_size,
                              hipStream_t stream) {
    gru_fused<<<dim3(Bsz / 8), dim3(512), 0, stream>>>(
        (const float*)d_in[0],
        (const float*)d_in[1], (const float*)d_in[2],
        (const float*)d_in[3], (const float*)d_in[4],
        (const float*)d_in[5], (const float*)d_in[6],
        (const float*)d_in[7], (const float*)d_in[8],
        (const float*)d_in[9], (const float*)d_in[10],
        (float*)d_out);
}

// Round 3
// 647.803 us; speedup vs baseline: 1.0738x; 1.0738x over previous
//
#include <hip/hip_runtime.h>

#define Bsz  2048
#define Tlen 512
#define Din  32
#define Hd   64
#define HS   72            // h-tile row stride in f16 elems (144B, 16B-aligned reads)
#define BUFE 2048          // f16 elems per h buffer (4096 B) -> XOR-toggle double buffer

typedef _Float16 half8 __attribute__((ext_vector_type(8)));
typedef float    f32x4 __attribute__((ext_vector_type(4)));

// weights pre-scaled by -log2(e) (r,z) and -2*log2(e) (n):
//   sigmoid(raw) = rcp(1 + exp2(g_scaled));  tanh(raw) = 2*rcp(1+exp2(y_scaled)) - 1
#define MFMA(a, b, c) __builtin_amdgcn_mfma_f32_16x16x32_f16((a), (b), (c), 0, 0, 0)

__device__ __forceinline__ half8 load8s(const float* p, float s) {
    half8 r;
#pragma unroll
    for (int j = 0; j < 8; ++j) r[j] = (_Float16)(p[j] * s);
    return r;
}
__device__ __forceinline__ half8 cvt8(float4 a, float4 b) {
    half8 r;
    r[0] = (_Float16)a.x; r[1] = (_Float16)a.y; r[2] = (_Float16)a.z; r[3] = (_Float16)a.w;
    r[4] = (_Float16)b.x; r[5] = (_Float16)b.y; r[6] = (_Float16)b.z; r[7] = (_Float16)b.w;
    return r;
}

// gates + state update + (optional) LDS writeback for 4 C-rows
__device__ __forceinline__ void gate_update(const f32x4& gr, const f32x4& gz,
                                            const f32x4& anx, const f32x4& anh,
                                            float hst[4], _Float16* dst, bool wr) {
#pragma unroll
    for (int r = 0; r < 4; ++r) {
        float rr = __builtin_amdgcn_rcpf(1.0f + __builtin_amdgcn_exp2f(gr[r]));
        float zz = __builtin_amdgcn_rcpf(1.0f + __builtin_amdgcn_exp2f(gz[r]));
        float yy = anx[r] + rr * anh[r];
        float tt = __builtin_amdgcn_rcpf(1.0f + __builtin_amdgcn_exp2f(yy));
        float nn = 2.0f * tt - 1.0f;
        hst[r] = nn + zz * (hst[r] - nn);
        if (wr) dst[r * HS] = (_Float16)hst[r];
    }
}

__global__ __launch_bounds__(512, 2)
void gru_fused(const float* __restrict__ x,
               const float* __restrict__ Wih0, const float* __restrict__ Whh0,
               const float* __restrict__ bih0, const float* __restrict__ bhh0,
               const float* __restrict__ Wih1, const float* __restrict__ Whh1,
               const float* __restrict__ bih1, const float* __restrict__ bhh1,
               const float* __restrict__ fcw,  const float* __restrict__ fcb,
               float* __restrict__ out)
{
    // arena: h1 buffers at [0],[BUFE]; h2 buffers at [2*BUFE],[3*BUFE]
    __shared__ _Float16 arena[4 * BUFE];
    __shared__ float hfin[8][Hd];

    const int tid  = threadIdx.x;
    const int lane = tid & 63;
    const int wave = tid >> 6;
    const int grp  = wave >> 2;            // 0 = layer1 waves, 1 = layer2 waves
    const int wg   = wave & 3;             // which 16 gate-cols this wave owns
    const int m    = lane & 15;            // A-frag row (batch); m>=8 ghost
    const int quad = lane >> 4;            // k-chunk (A/B), row-group (C/D)
    const int col  = (wg << 4) + m;        // gate/h column 0..63
    const int b0   = blockIdx.x << 3;      // 8 batches per block

    for (int idx = tid; idx < 4 * BUFE; idx += 512) arena[idx] = (_Float16)0.f;

    const float sRZ = -1.44269504f;        // -log2(e)
    const float sN  = -2.88539008f;        // -2*log2(e)

    // ---- persistent pre-scaled weight B-fragments (B[k][n] = W[n][k]) ----
    half8 wx[2][3], wh[2][3];
    float brz0, brz1, bin_, bhn_;

    if (grp == 0) {
        wx[0][0] = load8s(Wih0 + (      col) * Din + quad * 8, sRZ);
        wx[0][1] = load8s(Wih0 + ( 64 + col) * Din + quad * 8, sRZ);
        wx[0][2] = load8s(Wih0 + (128 + col) * Din + quad * 8, sN);
#pragma unroll
        for (int kb = 0; kb < 2; ++kb) {
            wh[kb][0] = load8s(Whh0 + (      col) * Hd + kb * 32 + quad * 8, sRZ);
            wh[kb][1] = load8s(Whh0 + ( 64 + col) * Hd + kb * 32 + quad * 8, sRZ);
            wh[kb][2] = load8s(Whh0 + (128 + col) * Hd + kb * 32 + quad * 8, sN);
        }
        brz0 = sRZ * (bih0[col] + bhh0[col]);
        brz1 = sRZ * (bih0[64 + col] + bhh0[64 + col]);
        bin_ = sN * bih0[128 + col];
        bhn_ = sN * bhh0[128 + col];
    } else {
#pragma unroll
        for (int kb = 0; kb < 2; ++kb) {
            wx[kb][0] = load8s(Wih1 + (      col) * Hd + kb * 32 + quad * 8, sRZ);
            wx[kb][1] = load8s(Wih1 + ( 64 + col) * Hd + kb * 32 + quad * 8, sRZ);
            wx[kb][2] = load8s(Wih1 + (128 + col) * Hd + kb * 32 + quad * 8, sN);
            wh[kb][0] = load8s(Whh1 + (      col) * Hd + kb * 32 + quad * 8, sRZ);
            wh[kb][1] = load8s(Whh1 + ( 64 + col) * Hd + kb * 32 + quad * 8, sRZ);
            wh[kb][2] = load8s(Whh1 + (128 + col) * Hd + kb * 32 + quad * 8, sN);
        }
        brz0 = sRZ * (bih1[col] + bhh1[col]);
        brz1 = sRZ * (bih1[64 + col] + bhh1[64 + col]);
        bin_ = sN * bih1[128 + col];
        bhn_ = sN * bhh1[128 + col];
    }

    // x prefetch (L1 waves). Ghost lanes (m>=8) alias batch m-8 (bounded, discarded).
    const float* xp = x + (size_t)(b0 + (m & 7)) * Tlen * Din + quad * 8;
    float4 xa, xb;
    if (grp == 0) { xa = *(const float4*)xp; xb = *(const float4*)(xp + 4); }

    const int rdoff = m * HS + quad * 8;          // lane part of A-read address
    const int wroff = (quad * 4) * HS + col;      // lane part of C-write address
    float hst[4] = {0.f, 0.f, 0.f, 0.f};
    __syncthreads();

    int ro = BUFE;                                // peel-0 reads zeros from buf1

    // ---------- peel i = 0 : L1 only; h1[-1]=0 so h-side MFMAs are skipped ----------
    if (grp == 0) {
        const float* xn = xp + Din;               // prefetch x[1]
        float4 pa = *(const float4*)xn, pb = *(const float4*)(xn + 4);
        half8 ax = cvt8(xa, xb);
        f32x4 gr  = {brz0, brz0, brz0, brz0};
        f32x4 gz  = {brz1, brz1, brz1, brz1};
        f32x4 anx = {bin_, bin_, bin_, bin_};
        f32x4 anh = {bhn_, bhn_, bhn_, bhn_};
        gr  = MFMA(ax, wx[0][0], gr);
        gz  = MFMA(ax, wx[0][1], gz);
        anx = MFMA(ax, wx[0][2], anx);
        gate_update(gr, gz, anx, anh, hst, arena + ((ro ^ BUFE) + wroff), true);
        xa = pa; xb = pb; xp = xn;
    }
    __syncthreads();
    ro ^= BUFE;                                   // -> 0

    // ---------- main: i = 1..511, both groups active, no predicates ----------
    for (int i = 1; i < Tlen; ++i) {
        const int wo = ro ^ BUFE;
        if (grp == 0) {
            const float* xn = xp + ((i + 1 < Tlen) ? Din : 0);
            float4 pa = *(const float4*)xn, pb = *(const float4*)(xn + 4);
            half8 ax = cvt8(xa, xb);
            const _Float16* s1 = arena + (ro + rdoff);
            half8 ah0 = *(const half8*)s1;
            half8 ah1 = *(const half8*)(s1 + 32);
            f32x4 arx = {brz0, brz0, brz0, brz0};
            f32x4 azx = {brz1, brz1, brz1, brz1};
            f32x4 anx = {bin_, bin_, bin_, bin_};
            f32x4 arh = {0.f, 0.f, 0.f, 0.f};
            f32x4 azh = {0.f, 0.f, 0.f, 0.f};
            f32x4 anh = {bhn_, bhn_, bhn_, bhn_};
            // h-side first (critical path from ds_read); depth-2 chains
            arh = MFMA(ah0, wh[0][0], arh); arh = MFMA(ah1, wh[1][0], arh);
            azh = MFMA(ah0, wh[0][1], azh); azh = MFMA(ah1, wh[1][1], azh);
            anh = MFMA(ah0, wh[0][2], anh); anh = MFMA(ah1, wh[1][2], anh);
            arx = MFMA(ax, wx[0][0], arx);
            azx = MFMA(ax, wx[0][1], azx);
            anx = MFMA(ax, wx[0][2], anx);
            f32x4 gr = arx + arh, gz = azx + azh;
            gate_update(gr, gz, anx, anh, hst, arena + (wo + wroff), true);
            xa = pa; xb = pb; xp = xn;
        } else {
            const _Float16* s1 = arena + (ro + rdoff);            // h1[i-1]
            const _Float16* s2 = s1 + 2 * BUFE;                   // h2[i-2]
            half8 ax0 = *(const half8*)s1;
            half8 ax1 = *(const half8*)(s1 + 32);
            half8 ah0 = *(const half8*)s2;
            half8 ah1 = *(const half8*)(s2 + 32);
            f32x4 arx = {brz0, brz0, brz0, brz0};
            f32x4 azx = {brz1, brz1, brz1, brz1};
            f32x4 anx = {bin_, bin_, bin_, bin_};
            f32x4 arh = {0.f, 0.f, 0.f, 0.f};
            f32x4 azh = {0.f, 0.f, 0.f, 0.f};
            f32x4 anh = {bhn_, bhn_, bhn_, bhn_};
            arx = MFMA(ax0, wx[0][0], arx); arx = MFMA(ax1, wx[1][0], arx);
            azx = MFMA(ax0, wx[0][1], azx); azx = MFMA(ax1, wx[1][1], azx);
            anx = MFMA(ax0, wx[0][2], anx); anx = MFMA(ax1, wx[1][2], anx);
            arh = MFMA(ah0, wh[0][0], arh); arh = MFMA(ah1, wh[1][0], arh);
            azh = MFMA(ah0, wh[0][1], azh); azh = MFMA(ah1, wh[1][1], azh);
            anh = MFMA(ah0, wh[0][2], anh); anh = MFMA(ah1, wh[1][2], anh);
            f32x4 gr = arx + arh, gz = azx + azh;
            gate_update(gr, gz, anx, anh, hst, arena + (2 * BUFE + wo + wroff), true);
        }
        __syncthreads();
        ro = wo;
    }

    // ---------- peel i = T : L2 only, computes h2[T-1], no LDS writeback ----------
    if (grp == 1) {
        const _Float16* s1 = arena + (ro + rdoff);
        const _Float16* s2 = s1 + 2 * BUFE;
        half8 ax0 = *(const half8*)s1;
        half8 ax1 = *(const half8*)(s1 + 32);
        half8 ah0 = *(const half8*)s2;
        half8 ah1 = *(const half8*)(s2 + 32);
        f32x4 arx = {brz0, brz0, brz0, brz0};
        f32x4 azx = {brz1, brz1, brz1, brz1};
        f32x4 anx = {bin_, bin_, bin_, bin_};
        f32x4 arh = {0.f, 0.f, 0.f, 0.f};
        f32x4 azh = {0.f, 0.f, 0.f, 0.f};
        f32x4 anh = {bhn_, bhn_, bhn_, bhn_};
        arx = MFMA(ax0, wx[0][0], arx); arx = MFMA(ax1, wx[1][0], arx);
        azx = MFMA(ax0, wx[0][1], azx); azx = MFMA(ax1, wx[1][1], azx);
        anx = MFMA(ax0, wx[0][2], anx); anx = MFMA(ax1, wx[1][2], anx);
        arh = MFMA(ah0, wh[0][0], arh); arh = MFMA(ah1, wh[1][0], arh);
        azh = MFMA(ah0, wh[0][1], azh); azh = MFMA(ah1, wh[1][1], azh);
        anh = MFMA(ah0, wh[0][2], anh); anh = MFMA(ah1, wh[1][2], anh);
        f32x4 gr = arx + arh, gz = azx + azh;
        gate_update(gr, gz, anx, anh, hst, nullptr, false);
        if (quad < 2) {                            // rows 0..7 are real
#pragma unroll
            for (int r = 0; r < 4; ++r) hfin[quad * 4 + r][col] = hst[r];
        }
    }
    __syncthreads();
    if (tid < 8) {                                 // FC head
        float acc = fcb[0];
        for (int c = 0; c < Hd; ++c) acc += hfin[tid][c] * fcw[c];
        out[b0 + tid] = acc;
    }
}

extern "C" void kernel_launch(void* const* d_in, const int* in_sizes, int n_in,
                              void* d_out, int out_size, void* d_ws, size_t ws_size,
                              hipStream_t stream) {
    gru_fused<<<dim3(Bsz / 8), dim3(512), 0, stream>>>(
        (const float*)d_in[0],
        (const float*)d_in[1], (const float*)d_in[2],
        (const float*)d_in[3], (const float*)d_in[4],
        (const float*)d_in[5], (const float*)d_in[6],
        (const float*)d_in[7], (const float*)d_in[8],
        (const float*)d_in[9], (const float*)d_in[10],
        (float*)d_out);
}